// Round 5
// baseline (174.375 us; speedup 1.0000x reference)
//
#include <hip/hip_runtime.h>
#include <hip/hip_fp16.h>
#include <math.h>

#define B_ 4
#define K_ 4
#define D_ 96
#define L_ 2048
#define N_ 16
#define R_ 6
#define C_ 38          // R + 2N

__device__ __forceinline__ float softplus_f(float x) {
    return fmaxf(x, 0.f) + __logf(1.f + __expf(-fabsf(x)));
}

#if __has_builtin(__builtin_amdgcn_exp2f)
__device__ __forceinline__ float exp2_fast(float x) { return __builtin_amdgcn_exp2f(x); }
#else
__device__ __forceinline__ float exp2_fast(float x) { return __expf(0.6931471805599453f * x); }
#endif

__device__ __forceinline__ float h2f(const uint4& v, int e) {
    return __half2float(((const __half*)&v)[e]);
}

// BC layout (fp16, chunk-interleaved for wave-coalesced scan reads):
//   uint4 (=8 halfs) at index (((bk*8 + i)*4 + j)*256 + t), where l = t*8+i
//   j=0: B n0..7   j=1: B n8..15   j=2: C n0..7   j=3: C n8..15

// ---------------------------------------------------------------------------
// Proj: grid (B*K, 8, 6), block 256, ONE l per thread (3 waves/SIMD of work,
// vs R4's 1.5 — proj was latency-starved at 384 blocks).
//   cg 0,1 -> B n-octet cg ; cg 2,3 -> C n-octet cg-2 ; cg 4 -> dts r0..3 ;
//   cg 5 -> dts r4..5
// ---------------------------------------------------------------------------
__global__ __launch_bounds__(256) void proj_kernel(
    const float* __restrict__ xs, const float* __restrict__ xpw,
    uint4* __restrict__ BCc, float* __restrict__ dts_ws)
{
    __shared__ float sW[8 * D_];
    const int bk = blockIdx.x;
    const int k = bk & 3;
    const int cg = blockIdx.z;
    const int tid = threadIdx.x;

    int c0, nrows;
    if (cg < 2)       { c0 = R_ + cg * 8;            nrows = 8; }
    else if (cg < 4)  { c0 = R_ + 16 + (cg - 2) * 8; nrows = 8; }
    else if (cg == 4) { c0 = 0;                      nrows = 4; }
    else              { c0 = 4;                      nrows = 2; }

    for (int i = tid; i < 8 * D_; i += 256) {
        if (i < nrows * D_) sW[i] = xpw[(k * C_ + c0 + i / D_) * D_ + (i % D_)];
        else sW[i] = 0.f;
    }
    __syncthreads();

    const int l = blockIdx.y * 256 + tid;
    const float* Xl = xs + (size_t)bk * D_ * L_ + l;

    float acc[8];
#pragma unroll
    for (int r = 0; r < 8; ++r) acc[r] = 0.f;

    // Fully unrolled: compiler batches the 96 independent coalesced loads
    // deeply ahead of the fma stream.
#pragma unroll
    for (int d = 0; d < D_; ++d) {
        const float xv = Xl[d * L_];
#pragma unroll
        for (int r = 0; r < 8; ++r)
            acc[r] = fmaf(sW[r * D_ + d], xv, acc[r]);
    }

    if (cg < 4) {
        const int j = cg;
        const int i = l & 7, t = l >> 3;
        union { __half h[8]; uint4 v; } p;
#pragma unroll
        for (int e = 0; e < 8; ++e) p.h[e] = __float2half(acc[e]);
        BCc[(((size_t)bk * 8 + i) * 4 + j) * 256 + t] = p.v;
    } else {
        const int rbase = (cg == 4) ? 0 : 4;
        const int rcnt = (cg == 4) ? 4 : 2;
        for (int r = 0; r < rcnt; ++r)
            dts_ws[((size_t)bk * R_ + rbase + r) * L_ + l] = acc[r];
    }
}

// ---------------------------------------------------------------------------
// Scan: grid B*K*D, block 256; thread owns l in [tid*8, tid*8+8).
// __launch_bounds__(256,4): cap VGPR at 128 -> 4 waves/SIMD resident.
// A pre-scaled by log2e -> dA is one v_mul + v_exp_f32. fp16 B/C consumed
// inline (v_mad_mix), no explicit cvt arrays, no manual prefetch.
// ---------------------------------------------------------------------------
__global__ __launch_bounds__(256, 4) void scan_kernel(
    const float* __restrict__ xs, const float* __restrict__ A_logs,
    const float* __restrict__ Ds, const float* __restrict__ dtw,
    const float* __restrict__ dtb, const float* __restrict__ dts_ws,
    const uint4* __restrict__ BCc, float* __restrict__ out)
{
    __shared__ float sAw[4][N_];
    __shared__ float sBw[4][N_];

    const int bkd = blockIdx.x;
    const int d = bkd % D_;
    const int bk = bkd / D_;
    const int k = bk & 3;
    const int kd = k * D_ + d;
    const int tid = threadIdx.x;
    const int lane = tid & 63;
    const int wave = tid >> 6;

    const uint4* BC = BCc + (size_t)bk * 8 * 4 * 256;

    // xs chunk -> registers
    const float4* xv4 = (const float4*)(xs + (size_t)bkd * L_);
    const float4 xa = xv4[tid * 2], xb = xv4[tid * 2 + 1];
    float x[8] = {xa.x, xa.y, xa.z, xa.w, xb.x, xb.y, xb.z, xb.w};

    // delta chunk
    float del[8];
    const float bias = dtb[kd];
#pragma unroll
    for (int j = 0; j < 8; ++j) del[j] = bias;
    const float* w2 = dtw + (size_t)kd * R_;
    const float4* dts4 = (const float4*)(dts_ws + (size_t)bk * R_ * L_);
#pragma unroll
    for (int r = 0; r < R_; ++r) {
        const float wr = w2[r];
        const float4 t0 = dts4[r * (L_ / 4) + tid * 2];
        const float4 t1 = dts4[r * (L_ / 4) + tid * 2 + 1];
        del[0] = fmaf(wr, t0.x, del[0]); del[1] = fmaf(wr, t0.y, del[1]);
        del[2] = fmaf(wr, t0.z, del[2]); del[3] = fmaf(wr, t0.w, del[3]);
        del[4] = fmaf(wr, t1.x, del[4]); del[5] = fmaf(wr, t1.y, del[5]);
        del[6] = fmaf(wr, t1.z, del[6]); del[7] = fmaf(wr, t1.w, del[7]);
    }
#pragma unroll
    for (int j = 0; j < 8; ++j) del[j] = softplus_f(del[j]);

    // A pre-scaled by log2(e): dA = exp2(del * A2)
    float A2[N_];
    const float* Ap = A_logs + (size_t)kd * N_;
#pragma unroll
    for (int n = 0; n < N_; ++n) A2[n] = -__expf(Ap[n]) * 1.44269504f;
    const float Dval = Ds[kd];

    float yv[8], dlx[8];
#pragma unroll
    for (int j = 0; j < 8; ++j) { yv[j] = Dval * x[j]; dlx[j] = del[j] * x[j]; }

    // Phase 1: per-chunk aggregate (a, b)
    float a[N_], b[N_];
#pragma unroll
    for (int n = 0; n < N_; ++n) { a[n] = 1.f; b[n] = 0.f; }
#pragma unroll
    for (int i = 0; i < 8; ++i) {
        const uint4 c0 = BC[(i * 4 + 0) * 256 + tid];
        const uint4 c1 = BC[(i * 4 + 1) * 256 + tid];
        const float dl = del[i], dx = dlx[i];
#pragma unroll
        for (int n = 0; n < N_; ++n) {
            const float Bn = (n < 8) ? h2f(c0, n) : h2f(c1, n - 8);
            const float dA = exp2_fast(dl * A2[n]);
            b[n] = fmaf(dA, b[n], dx * Bn);
            a[n] *= dA;
        }
    }

    // Phase 2a: wave-level inclusive scan
#pragma unroll
    for (int off = 1; off < 64; off <<= 1) {
#pragma unroll
        for (int n = 0; n < N_; ++n) {
            const float pa = __shfl_up(a[n], off, 64);
            const float pb = __shfl_up(b[n], off, 64);
            if (lane >= off) {
                b[n] = fmaf(a[n], pb, b[n]);
                a[n] *= pa;
            }
        }
    }
    // Phase 2b: cross-wave fixup
    if (lane == 63) {
#pragma unroll
        for (int n = 0; n < N_; ++n) { sAw[wave][n] = a[n]; sBw[wave][n] = b[n]; }
    }
    __syncthreads();

    // h at chunk start
    float h[N_];
#pragma unroll
    for (int n = 0; n < N_; ++n) {
        float ae = __shfl_up(a[n], 1, 64);
        float be = __shfl_up(b[n], 1, 64);
        if (lane == 0) { ae = 1.f; be = 0.f; }
        float wb = 0.f;
        for (int w = 0; w < wave; ++w) wb = fmaf(sAw[w][n], wb, sBw[w][n]);
        h[n] = fmaf(ae, wb, be);
    }

    // Phase 3: re-run chunk with true initial state, emit y
#pragma unroll
    for (int i = 0; i < 8; ++i) {
        const uint4 c0 = BC[(i * 4 + 0) * 256 + tid];
        const uint4 c1 = BC[(i * 4 + 1) * 256 + tid];
        const uint4 c2 = BC[(i * 4 + 2) * 256 + tid];
        const uint4 c3 = BC[(i * 4 + 3) * 256 + tid];
        const float dl = del[i], dx = dlx[i];
        float y = yv[i];
#pragma unroll
        for (int n = 0; n < N_; ++n) {
            const float Bn = (n < 8) ? h2f(c0, n) : h2f(c1, n - 8);
            const float Cn = (n < 8) ? h2f(c2, n) : h2f(c3, n - 8);
            const float dA = exp2_fast(dl * A2[n]);
            h[n] = fmaf(dA, h[n], dx * Bn);
            y = fmaf(h[n], Cn, y);
        }
        yv[i] = y;
    }
    float4* ov = (float4*)(out + (size_t)bkd * L_);
    ov[tid * 2]     = make_float4(yv[0], yv[1], yv[2], yv[3]);
    ov[tid * 2 + 1] = make_float4(yv[4], yv[5], yv[6], yv[7]);
}

extern "C" void kernel_launch(void* const* d_in, const int* in_sizes, int n_in,
                              void* d_out, int out_size, void* d_ws, size_t ws_size,
                              hipStream_t stream) {
    const float* xs = (const float*)d_in[0];       // (B,K,D,L)
    const float* A_logs = (const float*)d_in[1];   // (K*D, N)
    const float* Ds = (const float*)d_in[2];       // (K*D,)
    const float* dtw = (const float*)d_in[3];      // (K,D,R)
    const float* dtb = (const float*)d_in[4];      // (K,D)
    const float* xpw = (const float*)d_in[5];      // (K,C,D)
    float* out = (float*)d_out;                    // (B,K,D,L) fp32

    uint4* BCc = (uint4*)d_ws;                     // 16*8*4*256 uint4 = 2 MB
    float* dts_ws = (float*)(BCc + (size_t)B_ * K_ * 8 * 4 * 256);  // 768 KB

    proj_kernel<<<dim3(B_ * K_, 8, 6), 256, 0, stream>>>(xs, xpw, BCc, dts_ws);
    scan_kernel<<<B_ * K_ * D_, 256, 0, stream>>>(
        xs, A_logs, Ds, dtw, dtb, dts_ws, BCc, out);
}

// Round 6
// 132.380 us; speedup vs baseline: 1.3172x; 1.3172x over previous
//
#include <hip/hip_runtime.h>
#include <hip/hip_fp16.h>
#include <math.h>

#define B_ 4
#define K_ 4
#define D_ 96
#define L_ 2048
#define N_ 16
#define R_ 6
#define C_ 38          // R + 2N

__device__ __forceinline__ float softplus_f(float x) {
    return fmaxf(x, 0.f) + __logf(1.f + __expf(-fabsf(x)));
}

#if __has_builtin(__builtin_amdgcn_exp2f)
__device__ __forceinline__ float exp2_fast(float x) { return __builtin_amdgcn_exp2f(x); }
#else
__device__ __forceinline__ float exp2_fast(float x) { return __expf(0.6931471805599453f * x); }
#endif

__device__ __forceinline__ float h2f(const uint4& v, int e) {
    return __half2float(((const __half*)&v)[e]);
}

// BC layout (fp16, chunk-interleaved for wave-coalesced scan reads):
//   uint4 (=8 halfs) at index (((bk*8 + i)*4 + j)*256 + t), where l = t*8+i
//   j=0: B n0..7   j=1: B n8..15   j=2: C n0..7   j=3: C n8..15

// ---------------------------------------------------------------------------
// Proj: grid (B*K, 8, 2), block 256, one l per thread.
//   cg 0 -> dts r0..5 + B n0..15 (22 rows);  cg 1 -> C n0..15 (16 rows)
// xs read only 2x total (was 6x). Weights in LDS transposed+padded
// [d][24] so the per-d read is 6 broadcast ds_read_b128 (was 22 b32).
// ---------------------------------------------------------------------------
__global__ __launch_bounds__(256) void proj_kernel(
    const float* __restrict__ xs, const float* __restrict__ xpw,
    uint4* __restrict__ BCc, float* __restrict__ dts_ws)
{
    __shared__ float sWt[D_][24];   // padded to 24 for 16B-aligned rows
    const int bk = blockIdx.x;
    const int k = bk & 3;
    const int cg = blockIdx.z;
    const int tid = threadIdx.x;
    const int c0 = (cg == 0) ? 0 : (R_ + N_);
    const int nr = (cg == 0) ? 22 : 16;

    for (int i = tid; i < nr * D_; i += 256) {
        const int r = i / D_, dd = i % D_;          // global read coalesced over dd
        sWt[dd][r] = xpw[(k * C_ + c0 + r) * D_ + dd];
    }
    __syncthreads();

    const int l = blockIdx.y * 256 + tid;
    const float* Xl = xs + (size_t)bk * D_ * L_ + l;
    const int i8 = l & 7, t8 = l >> 3;
    uint4* BCb = BCc + ((size_t)bk * 8 + i8) * 4 * 256 + t8;

    if (cg == 0) {
        float acc[22];
#pragma unroll
        for (int r = 0; r < 22; ++r) acc[r] = 0.f;
#pragma unroll
        for (int d = 0; d < D_; ++d) {
            const float xv = Xl[d * L_];
            float wv[24];
#pragma unroll
            for (int q = 0; q < 6; ++q)
                *(float4*)&wv[q * 4] = *(const float4*)&sWt[d][q * 4];
#pragma unroll
            for (int r = 0; r < 22; ++r) acc[r] = fmaf(wv[r], xv, acc[r]);
        }
#pragma unroll
        for (int r = 0; r < R_; ++r)
            dts_ws[((size_t)bk * R_ + r) * L_ + l] = acc[r];
        union { __half h[8]; uint4 v; } p0, p1;
#pragma unroll
        for (int e = 0; e < 8; ++e) {
            p0.h[e] = __float2half(acc[6 + e]);
            p1.h[e] = __float2half(acc[14 + e]);
        }
        BCb[0 * 256] = p0.v;   // B n0..7
        BCb[1 * 256] = p1.v;   // B n8..15
    } else {
        float acc[16];
#pragma unroll
        for (int r = 0; r < 16; ++r) acc[r] = 0.f;
#pragma unroll
        for (int d = 0; d < D_; ++d) {
            const float xv = Xl[d * L_];
            float wv[16];
#pragma unroll
            for (int q = 0; q < 4; ++q)
                *(float4*)&wv[q * 4] = *(const float4*)&sWt[d][q * 4];
#pragma unroll
            for (int r = 0; r < 16; ++r) acc[r] = fmaf(wv[r], xv, acc[r]);
        }
        union { __half h[8]; uint4 v; } p0, p1;
#pragma unroll
        for (int e = 0; e < 8; ++e) {
            p0.h[e] = __float2half(acc[e]);
            p1.h[e] = __float2half(acc[8 + e]);
        }
        BCb[2 * 256] = p0.v;   // C n0..7
        BCb[3 * 256] = p1.v;   // C n8..15
    }
}

// ---------------------------------------------------------------------------
// Scan: grid B*K*D, block 512. Group g = tid>>8 owns n in [8g, 8g+8);
// t = tid&255 owns l in [t*8, t*8+8). Halved per-thread state -> ~100 VGPR
// -> 5 waves/SIMD naturally (no forced bound, no spill). Group partial y's
// combined via padded LDS.
// ---------------------------------------------------------------------------
__global__ __launch_bounds__(512) void scan_kernel(
    const float* __restrict__ xs, const float* __restrict__ A_logs,
    const float* __restrict__ Ds, const float* __restrict__ dtw,
    const float* __restrict__ dtb, const float* __restrict__ dts_ws,
    const uint4* __restrict__ BCc, float* __restrict__ out)
{
    __shared__ float sAw[8][8];     // [global wave][n-local]
    __shared__ float sBw[8][8];
    __shared__ float sy[256][9];    // pad 9: conflict-free stride

    const int bkd = blockIdx.x;
    const int d = bkd % D_;
    const int bk = bkd / D_;
    const int k = bk & 3;
    const int kd = k * D_ + d;
    const int tid = threadIdx.x;
    const int g = tid >> 8;          // n-half
    const int t = tid & 255;         // l-chunk owner
    const int lane = tid & 63;
    const int gw = tid >> 6;         // global wave 0..7 (waves 0-3: g=0)

    const uint4* BC = BCc + (size_t)bk * 8 * 4 * 256;
    const int jB = g, jC = 2 + g;

    // xs chunk -> registers (duplicated across groups; L1 broadcast)
    const float4* xv4 = (const float4*)(xs + (size_t)bkd * L_);
    const float4 xa = xv4[t * 2], xb = xv4[t * 2 + 1];
    float x[8] = {xa.x, xa.y, xa.z, xa.w, xb.x, xb.y, xb.z, xb.w};

    // delta chunk (duplicated per group — identical loads, L1 hits)
    float del[8];
    const float bias = dtb[kd];
#pragma unroll
    for (int j = 0; j < 8; ++j) del[j] = bias;
    const float* w2 = dtw + (size_t)kd * R_;
    const float4* dts4 = (const float4*)(dts_ws + (size_t)bk * R_ * L_);
#pragma unroll
    for (int r = 0; r < R_; ++r) {
        const float wr = w2[r];
        const float4 t0 = dts4[r * (L_ / 4) + t * 2];
        const float4 t1 = dts4[r * (L_ / 4) + t * 2 + 1];
        del[0] = fmaf(wr, t0.x, del[0]); del[1] = fmaf(wr, t0.y, del[1]);
        del[2] = fmaf(wr, t0.z, del[2]); del[3] = fmaf(wr, t0.w, del[3]);
        del[4] = fmaf(wr, t1.x, del[4]); del[5] = fmaf(wr, t1.y, del[5]);
        del[6] = fmaf(wr, t1.z, del[6]); del[7] = fmaf(wr, t1.w, del[7]);
    }
#pragma unroll
    for (int j = 0; j < 8; ++j) del[j] = softplus_f(del[j]);

    // A pre-scaled by log2(e); this group's 8 n's only
    float A2[8];
    const float* Ap = A_logs + (size_t)kd * N_ + g * 8;
#pragma unroll
    for (int n = 0; n < 8; ++n) A2[n] = -__expf(Ap[n]) * 1.44269504f;
    const float Dval = Ds[kd];

    // Phase 1: per-chunk aggregate over this n-half
    float a[8], b[8];
#pragma unroll
    for (int n = 0; n < 8; ++n) { a[n] = 1.f; b[n] = 0.f; }
#pragma unroll
    for (int i = 0; i < 8; ++i) {
        const uint4 cB = BC[(i * 4 + jB) * 256 + t];
        const float dl = del[i];
        const float dx = dl * x[i];
#pragma unroll
        for (int n = 0; n < 8; ++n) {
            const float dA = exp2_fast(dl * A2[n]);
            b[n] = fmaf(dA, b[n], dx * h2f(cB, n));
            a[n] *= dA;
        }
    }

    // Phase 2a: wave-level inclusive scan (8 n's)
#pragma unroll
    for (int off = 1; off < 64; off <<= 1) {
#pragma unroll
        for (int n = 0; n < 8; ++n) {
            const float pa = __shfl_up(a[n], off, 64);
            const float pb = __shfl_up(b[n], off, 64);
            if (lane >= off) {
                b[n] = fmaf(a[n], pb, b[n]);
                a[n] *= pa;
            }
        }
    }
    // Phase 2b: cross-wave fixup (within group: waves g*4 .. g*4+3)
    if (lane == 63) {
#pragma unroll
        for (int n = 0; n < 8; ++n) { sAw[gw][n] = a[n]; sBw[gw][n] = b[n]; }
    }
    __syncthreads();

    float h[8];
#pragma unroll
    for (int n = 0; n < 8; ++n) {
        float ae = __shfl_up(a[n], 1, 64);
        float be = __shfl_up(b[n], 1, 64);
        if (lane == 0) { ae = 1.f; be = 0.f; }
        float wb = 0.f;
        for (int w = g * 4; w < gw; ++w) wb = fmaf(sAw[w][n], wb, sBw[w][n]);
        h[n] = fmaf(ae, wb, be);
    }

    // Phase 3: re-run chunk with true initial state; partial y per group
    float yv[8];
#pragma unroll
    for (int j = 0; j < 8; ++j) yv[j] = (g == 0) ? Dval * x[j] : 0.f;
#pragma unroll
    for (int i = 0; i < 8; ++i) {
        const uint4 cB = BC[(i * 4 + jB) * 256 + t];
        const uint4 cC = BC[(i * 4 + jC) * 256 + t];
        const float dl = del[i];
        const float dx = dl * x[i];
        float y = yv[i];
#pragma unroll
        for (int n = 0; n < 8; ++n) {
            const float dA = exp2_fast(dl * A2[n]);
            h[n] = fmaf(dA, h[n], dx * h2f(cB, n));
            y = fmaf(h[n], h2f(cC, n), y);
        }
        yv[i] = y;
    }

    // Combine group partials and store
    if (g == 1) {
#pragma unroll
        for (int j = 0; j < 8; ++j) sy[t][j] = yv[j];
    }
    __syncthreads();
    if (g == 0) {
#pragma unroll
        for (int j = 0; j < 8; ++j) yv[j] += sy[t][j];
        float4* ov = (float4*)(out + (size_t)bkd * L_);
        ov[t * 2]     = make_float4(yv[0], yv[1], yv[2], yv[3]);
        ov[t * 2 + 1] = make_float4(yv[4], yv[5], yv[6], yv[7]);
    }
}

extern "C" void kernel_launch(void* const* d_in, const int* in_sizes, int n_in,
                              void* d_out, int out_size, void* d_ws, size_t ws_size,
                              hipStream_t stream) {
    const float* xs = (const float*)d_in[0];       // (B,K,D,L)
    const float* A_logs = (const float*)d_in[1];   // (K*D, N)
    const float* Ds = (const float*)d_in[2];       // (K*D,)
    const float* dtw = (const float*)d_in[3];      // (K,D,R)
    const float* dtb = (const float*)d_in[4];      // (K,D)
    const float* xpw = (const float*)d_in[5];      // (K,C,D)
    float* out = (float*)d_out;                    // (B,K,D,L) fp32

    uint4* BCc = (uint4*)d_ws;                     // 16*8*4*256 uint4 = 2 MB
    float* dts_ws = (float*)(BCc + (size_t)B_ * K_ * 8 * 4 * 256);  // 768 KB

    proj_kernel<<<dim3(B_ * K_, 8, 2), 256, 0, stream>>>(xs, xpw, BCc, dts_ws);
    scan_kernel<<<B_ * K_ * D_, 512, 0, stream>>>(
        xs, A_logs, Ds, dtw, dtb, dts_ws, BCc, out);
}